// Round 1
// baseline (136.050 us; speedup 1.0000x reference)
//
#include <hip/hip_runtime.h>
#include <hip/hip_bf16.h>

// Problem constants (fixed by setup_inputs): B=8, T=2048, D=1024, positions in [0,64).
#define NB 8
#define NT 2048
#define ND 1024
#define NP 64          // position grid side
#define CAP 2048       // max tokens per bucket (worst case all T in one bucket)

// ---------------------------------------------------------------------------
// Workspace layout (byte offsets, all 512-aligned):
//   G2f    : 128 floats  g2[k] = exp(-(k-63)^2/512), valid k in [0,126]   @ 0
//   cntv   : NB*64 int                                                     @ 512
//   cnth   : NB*64 int                                                     @ 2560
//   cntB1  : NB*64*64 float  (= sum of g over tokens: [b][pv][ph])         @ 4608
//   tokv   : NB*64*CAP int   (token ids bucketed by posv)                  @ 135680
//   tokh   : NB*64*CAP int   (token ids bucketed by posh)                  @ 4329984
//   B1     : (NB or 1)*64*64*1024 float                                    @ 8524288
// ---------------------------------------------------------------------------
#define OFF_G2    0
#define OFF_CNTV  512
#define OFF_CNTH  2560
#define OFF_CNTB1 4608
#define OFF_TOKV  135680
#define OFF_TOKH  4329984
#define OFF_B1    8524288
#define B1_SLAB   ((size_t)64 * 64 * 1024 * 4)   // bytes per batch slab (16 MB)

// K1: build deterministic CSR bucket lists (by posv and by posh) via wave ballot
// compaction (no atomics -> bitwise deterministic). Block 0 also fills the g table.
__global__ __launch_bounds__(256) void k1_bucket(
    const int* __restrict__ posv, const int* __restrict__ posh,
    int* __restrict__ tokv, int* __restrict__ tokh,
    int* __restrict__ cntv, int* __restrict__ cnth,
    float* __restrict__ G2f)
{
    int b    = blockIdx.x >> 3;      // NB*8 blocks
    int blk  = blockIdx.x & 7;
    int wave = threadIdx.x >> 6;
    int lane = threadIdx.x & 63;

    if (blockIdx.x == 0 && threadIdx.x < 128) {
        int k = (int)threadIdx.x;
        if (k < 127) {
            int r = k - 63;
            G2f[k] = expf(-(float)(r * r) * (1.0f / 512.0f));
        } else {
            G2f[k] = 0.0f;
        }
    }

    int wtask = blk * 4 + wave;                 // 0..31 within batch
    for (int i = 0; i < 4; i++) {
        int task   = wtask * 4 + i;             // 0..127
        int bucket = task & 63;
        int use_ph = (task >> 6) & 1;
        const int* pos = use_ph ? posh : posv;
        int* tok = (use_ph ? tokh : tokv) + ((size_t)(b * 64 + bucket)) * CAP;
        int* cnt = use_ph ? cnth : cntv;
        int cursor = 0;
        for (int k = 0; k < NT / 64; k++) {
            int t = k * 64 + lane;
            int v = pos[b * NT + t];
            unsigned long long m = __ballot(v == bucket);
            if (v == bucket)
                tok[cursor + __popcll(m & ((1ull << lane) - 1ull))] = t;
            cursor += (int)__popcll(m);
        }
        if (lane == 0) cnt[b * 64 + bucket] = cursor;
    }
}

// K2: h-direction conv straight from tokens (skips materializing the raw grid):
//   B1[b][pv][ph][d] = sum_{t: posv_t==pv} g(ph - posh_t) * x[b][t][d]
// Thread owns one d, register-accumulates all 64 ph. g-window address is
// wave-uniform (readfirstlane) -> scalar loads, FMA-pipe bound.
// Also emits cntB1[b][pv][ph] = sum_t g(ph - posh_t) (the count conv).
__global__ __launch_bounds__(256) void k2_convh(
    const float* __restrict__ x, const int* __restrict__ posh,
    const int* __restrict__ tokv, const int* __restrict__ cntv,
    const float* __restrict__ G2f, float* __restrict__ B1,
    float* __restrict__ cntB1, int b0)
{
    int p   = blockIdx.x & 63;
    int b   = b0 + (blockIdx.x >> 6);
    int d   = (blockIdx.y << 8) + threadIdx.x;
    int tid = threadIdx.x;

    int n = cntv[b * 64 + p];
    const int* toks = tokv + ((size_t)(b * 64 + p)) * CAP;

    float acc[64];
#pragma unroll
    for (int q = 0; q < 64; q++) acc[q] = 0.0f;

    __shared__ int s_t[256];
    __shared__ int s_ph[256];

    for (int base = 0; base < n; base += 256) {
        int m = min(256, n - base);
        __syncthreads();
        if (tid < m) {
            int t = toks[base + tid];
            s_t[tid]  = t;
            s_ph[tid] = posh[b * NT + t];
        }
        __syncthreads();
        for (int i = 0; i < m; i++) {
            int t  = __builtin_amdgcn_readfirstlane(s_t[i]);
            int ph = __builtin_amdgcn_readfirstlane(s_ph[i]);
            float xv = x[((size_t)(b * NT + t) << 10) + d];
            const float* gw = G2f + (63 - ph);
#pragma unroll
            for (int q = 0; q < 64; q++)
                acc[q] = fmaf(gw[q], xv, acc[q]);
        }
    }

    float* B1b = B1 + ((size_t)(b - b0) << 22);
#pragma unroll
    for (int q = 0; q < 64; q++)
        B1b[(((size_t)(p * 64 + q)) << 10) + d] = acc[q];

    // count-conv row (only one d-chunk needs to do it)
    if (blockIdx.y == 0 && tid < 64) {
        float c = 0.0f;
        for (int i = 0; i < n; i++) {
            int t  = toks[i];
            int ph = posh[b * NT + t];
            c += G2f[63 + tid - ph];
        }
        cntB1[(b * 64 + p) * 64 + tid] = c;
    }
}

// K3: v-direction conv fused with the per-token gather + normalization:
//   out[b][t][d] = ( sum_j g(j - posv_t) * B1[b][j][posh_t][d] ) / denom_t
// Block = (b, ph-bucket, d-chunk). The B1 column is shared by every token in
// the bucket -> load it once into 64 registers per thread. Per-token weights
// are wave-uniform scalar loads; 4 independent FMA chains for ILP.
__global__ __launch_bounds__(256) void k3_convv(
    const int* __restrict__ posv,
    const int* __restrict__ tokh, const int* __restrict__ cnth,
    const float* __restrict__ G2f, const float* __restrict__ B1,
    const float* __restrict__ cntB1, float* __restrict__ out, int b0)
{
    int p   = blockIdx.x & 63;          // ph bucket
    int b   = b0 + (blockIdx.x >> 6);
    int d   = (blockIdx.y << 8) + threadIdx.x;
    int tid = threadIdx.x;

    int n = cnth[b * 64 + p];
    if (n == 0) return;                 // uniform across block: safe

    const int* toks = tokh + ((size_t)(b * 64 + p)) * CAP;
    const float* B1b = B1 + ((size_t)(b - b0) << 22);

    float col[64];
#pragma unroll
    for (int j = 0; j < 64; j++)
        col[j] = B1b[(((size_t)(j * 64 + p)) << 10) + d];

    __shared__ int   s_t[256];
    __shared__ int   s_pv[256];
    __shared__ float s_inv[256];

    for (int base = 0; base < n; base += 256) {
        int m = min(256, n - base);
        __syncthreads();
        if (tid < m) {
            int t  = toks[base + tid];
            int pv = posv[b * NT + t];
            float den = 0.0f;
            for (int j = 0; j < 64; j++)
                den += G2f[63 - pv + j] * cntB1[(b * 64 + j) * 64 + p];
            s_t[tid]   = t;
            s_pv[tid]  = pv;
            s_inv[tid] = 1.0f / den;
        }
        __syncthreads();
        for (int i = 0; i < m; i++) {
            int t  = __builtin_amdgcn_readfirstlane(s_t[i]);
            int pv = __builtin_amdgcn_readfirstlane(s_pv[i]);
            float inv = s_inv[i];
            const float* gw = G2f + (63 - pv);
            float a0 = 0.f, a1 = 0.f, a2 = 0.f, a3 = 0.f;
#pragma unroll
            for (int j = 0; j < 64; j += 4) {
                a0 = fmaf(gw[j + 0], col[j + 0], a0);
                a1 = fmaf(gw[j + 1], col[j + 1], a1);
                a2 = fmaf(gw[j + 2], col[j + 2], a2);
                a3 = fmaf(gw[j + 3], col[j + 3], a3);
            }
            out[((size_t)(b * NT + t) << 10) + d] = ((a0 + a1) + (a2 + a3)) * inv;
        }
    }
}

// Safety-net fallback (no workspace needed): direct O(T^2 * D) attention.
// Only used if ws_size is unexpectedly tiny.
__global__ __launch_bounds__(256) void k_naive(
    const float* __restrict__ x, const int* __restrict__ posv,
    const int* __restrict__ posh, float* __restrict__ out)
{
    int t   = blockIdx.x & (NT - 1);
    int b   = blockIdx.x >> 11;
    int tid = threadIdx.x;

    __shared__ float s_w[NT];
    __shared__ float s_red[256];

    int pvt = posv[b * NT + t];
    int pht = posh[b * NT + t];

    float dsum = 0.0f;
    for (int s = tid; s < NT; s += 256) {
        int dv = pvt - posv[b * NT + s];
        int dh = pht - posh[b * NT + s];
        float w = expf(-(float)(dv * dv + dh * dh) * (1.0f / 512.0f));
        s_w[s] = w;
        dsum += w;
    }
    s_red[tid] = dsum;
    __syncthreads();
    for (int off = 128; off > 0; off >>= 1) {
        if (tid < off) s_red[tid] += s_red[tid + off];
        __syncthreads();
    }
    float inv = 1.0f / s_red[0];

    float a0 = 0.f, a1 = 0.f, a2 = 0.f, a3 = 0.f;
    for (int s = 0; s < NT; s++) {
        float w = s_w[s];
        const float* xr = x + ((size_t)(b * NT + s) << 10);
        a0 = fmaf(w, xr[tid + 0],   a0);
        a1 = fmaf(w, xr[tid + 256], a1);
        a2 = fmaf(w, xr[tid + 512], a2);
        a3 = fmaf(w, xr[tid + 768], a3);
    }
    size_t ob = ((size_t)(b * NT + t) << 10) + tid;
    out[ob + 0]   = a0 * inv;
    out[ob + 256] = a1 * inv;
    out[ob + 512] = a2 * inv;
    out[ob + 768] = a3 * inv;
}

extern "C" void kernel_launch(void* const* d_in, const int* in_sizes, int n_in,
                              void* d_out, int out_size, void* d_ws, size_t ws_size,
                              hipStream_t stream) {
    const float* x    = (const float*)d_in[0];
    const int*   posv = (const int*)d_in[1];
    const int*   posh = (const int*)d_in[2];
    float*       out  = (float*)d_out;

    char* ws = (char*)d_ws;
    float* G2f   = (float*)(ws + OFF_G2);
    int*   cntv  = (int*)(ws + OFF_CNTV);
    int*   cnth  = (int*)(ws + OFF_CNTH);
    float* cntB1 = (float*)(ws + OFF_CNTB1);
    int*   tokv  = (int*)(ws + OFF_TOKV);
    int*   tokh  = (int*)(ws + OFF_TOKH);
    float* B1    = (float*)(ws + OFF_B1);

    const size_t needFull = (size_t)OFF_B1 + (size_t)NB * B1_SLAB;   // ~143 MB
    const size_t needLoop = (size_t)OFF_B1 + B1_SLAB;                // ~25 MB

    if (ws_size >= needFull) {
        k1_bucket<<<NB * 8, 256, 0, stream>>>(posv, posh, tokv, tokh, cntv, cnth, G2f);
        k2_convh<<<dim3(NB * 64, ND / 256), 256, 0, stream>>>(
            x, posh, tokv, cntv, G2f, B1, cntB1, 0);
        k3_convv<<<dim3(NB * 64, ND / 256), 256, 0, stream>>>(
            posv, tokh, cnth, G2f, B1, cntB1, out, 0);
    } else if (ws_size >= needLoop) {
        k1_bucket<<<NB * 8, 256, 0, stream>>>(posv, posh, tokv, tokh, cntv, cnth, G2f);
        for (int b = 0; b < NB; b++) {
            k2_convh<<<dim3(64, ND / 256), 256, 0, stream>>>(
                x, posh, tokv, cntv, G2f, B1, cntB1, b);
            k3_convv<<<dim3(64, ND / 256), 256, 0, stream>>>(
                posv, tokh, cnth, G2f, B1, cntB1, out, b);
        }
    } else {
        k_naive<<<NB * NT, 256, 0, stream>>>(x, posv, posh, out);
    }
}